// Round 1
// baseline (201.254 us; speedup 1.0000x reference)
//
#include <hip/hip_runtime.h>
#include <hip/hip_cooperative_groups.h>
#include <math.h>

namespace cg = cooperative_groups;

#define N_ATOMS 400
#define N_RES   100
#define DT      0.02f
#define PI_D    3.14159265358979323846
#define NBLK    100
#define NTHR    256

// ---------- small float3 helpers ----------
struct V3 { float x, y, z; };
__device__ __forceinline__ V3 v3(float x, float y, float z) { V3 r{x,y,z}; return r; }
__device__ __forceinline__ V3 sub(V3 a, V3 b) { return v3(a.x-b.x, a.y-b.y, a.z-b.z); }
__device__ __forceinline__ V3 neg(V3 a) { return v3(-a.x, -a.y, -a.z); }
__device__ __forceinline__ V3 scale(V3 a, float s) { return v3(a.x*s, a.y*s, a.z*s); }
__device__ __forceinline__ float dot3(V3 a, V3 b) { return a.x*b.x + a.y*b.y + a.z*b.z; }
__device__ __forceinline__ V3 cross3(V3 a, V3 b) {
    return v3(a.y*b.z - a.z*b.y, a.z*b.x - a.x*b.z, a.x*b.y - a.y*b.x);
}
__device__ __forceinline__ float vnorm(V3 a) {
    float s = dot3(a, a);
    return s > 0.0f ? sqrtf(s) : 0.0f;   // safe_norm semantics
}
__device__ __forceinline__ V3 normalize3(V3 a) {
    float n = fmaxf(vnorm(a), 1e-12f);
    return scale(a, 1.0f/n);
}

// ---------- bin index helpers (uniform grids; argmin == nearest, clamped) ----------
__device__ __forceinline__ int clampi(int i, int lo, int hi) {
    return i < lo ? lo : (i > hi ? hi : i);
}
__device__ __forceinline__ int bin_dist(float d) {
    const float INV = (float)(137.0/14.9);     // linspace(1.0, 15.9, 138)
    return clampi((int)floorf((d - 1.0f)*INV + 0.5f), 0, 137);
}
__device__ __forceinline__ int bin_ang(float a) {
    const float C0  = (float)(PI_D/3.0 + 1.5*((PI_D - PI_D/3.0)/140.0));
    const float INV = (float)(140.0/(PI_D - PI_D/3.0));
    return clampi((int)floorf((a - C0)*INV + 0.5f), 0, 137);
}
__device__ __forceinline__ int bin_dih(float a) {
    const float C0  = (float)(-PI_D + 0.5*(2.0*PI_D/140.0));
    const float INV = (float)(140.0/(2.0*PI_D));
    return clampi((int)floorf((a - C0)*INV + 0.5f), 0, 139);
}

// ---------- bonded-term tables ----------
__constant__ int ANG_I[5][3]   = {{0,1,2},{1,2,0},{2,0,1},{0,1,3},{2,1,3}};
__constant__ int ANG_ACROSS[5] = {0,1,2,0,0};
__constant__ int DIH_I[5][4]   = {{2,0,1,2},{0,1,2,0},{1,2,0,1},{2,0,1,3},{3,1,2,0}};
__constant__ int DIH_ACROSS[5] = {3,1,2,3,1};

__device__ __forceinline__ V3 ldpos(const float* c, int res, int atom) {
    int b = (res*4 + atom)*3;
    return v3(c[b], c[b+1], c[b+2]);
}
__device__ __forceinline__ void addF(float* F, int res, int atom, V3 f) {
    int b = (res*4 + atom)*3;
    atomicAdd(&F[b],   f.x);
    atomicAdd(&F[b+1], f.y);
    atomicAdd(&F[b+2], f.z);
}

// bonded term for work item t (0..499 angles, 500..994 dihedrals); reads coords
// from c (LDS copy), accumulates into Fb (global, atomic).
__device__ __forceinline__ void bonded_item(int t, const float* c,
                              const float* __restrict__ ffa, const float* __restrict__ ffdih,
                              const int* __restrict__ ia, const int* __restrict__ idh,
                              float* __restrict__ Fb) {
    if (t < 500) {
        // -------- angles --------
        int ai = t/100, r = t%100;
        int across = ANG_ACROSS[ai];
        if (across == 0 || r < N_RES-1) {
            int i1 = ANG_I[ai][0], i2 = ANG_I[ai][1], i3 = ANG_I[ai][2];
            int o2 = (across == 2) ? 1 : 0;
            int o3 = (across != 0) ? 1 : 0;
            V3 p1 = ldpos(c, r,     i1);
            V3 p2 = ldpos(c, r+o2,  i2);
            V3 p3 = ldpos(c, r+o3,  i3);
            V3 ba = sub(p1, p2);
            V3 bc = sub(p3, p2);
            float ban = vnorm(ba), bcn = vnorm(bc);
            float ca = dot3(ba, bc) / (ban*bcn);
            ca = fminf(1.0f, fmaxf(-1.0f, ca));
            float ang = acosf(ca);
            int ind = bin_ang(ang);
            int potr = (across == 2) ? r+1 : r;
            const float* row = ffa + (ai*20 + ia[potr])*140;
            float f = 0.5f*(row[ind] - row[ind+2]);
            V3 cr = cross3(ba, bc);
            V3 fa = scale(normalize3(cross3(ba, cr)), f/ban);
            V3 fc = scale(normalize3(neg(cross3(bc, cr))), f/bcn);
            V3 fb = neg(v3(fa.x+fc.x, fa.y+fc.y, fa.z+fc.z));
            addF(Fb, r,     i1, fa);
            addF(Fb, r+o2,  i2, fb);
            addF(Fb, r+o3,  i3, fc);
        }
    } else if (t < 500 + 5*(N_RES-1)) {
        // -------- dihedrals --------
        int u = t - 500;
        int di = u/(N_RES-1), r = u%(N_RES-1);
        int across = DIH_ACROSS[di];
        int i1 = DIH_I[di][0], i2 = DIH_I[di][1], i3 = DIH_I[di][2], i4 = DIH_I[di][3];
        int o2 = (across == 3) ? 1 : 0;
        int o3 = (across >= 2) ? 1 : 0;
        int o4 = 1;
        V3 p1 = ldpos(c, r,     i1);
        V3 p2 = ldpos(c, r+o2,  i2);
        V3 p3 = ldpos(c, r+o3,  i3);
        V3 p4 = ldpos(c, r+o4,  i4);
        V3 ab = sub(p2, p1);
        V3 bc = sub(p3, p2);
        V3 cd = sub(p4, p3);
        V3 c1 = cross3(ab, bc);
        V3 c2 = cross3(bc, cd);
        float bcn = vnorm(bc);
        V3 cc = cross3(c1, c2);
        float y = dot3(cc, bc) / bcn;
        float x = dot3(c1, c2);
        float dih = atan2f(y, x);
        int ind = bin_dih(dih);
        int potr = (across == 1) ? r : r+1;
        const float* row = ffdih + (di*20 + idh[potr])*142;
        float f = 0.5f*(row[ind] - row[ind+2]);
        V3 fa = scale(normalize3(neg(c1)), f / vnorm(ab));
        V3 fd = scale(normalize3(c2),      f / vnorm(cd));
        float bsq = bcn*bcn;
        float t1 = dot3(ab, bc)/bsq;
        float t2 = dot3(cd, bc)/bsq;
        V3 fb = v3(-fa.x - t1*fa.x + t2*fd.x,
                   -fa.y - t1*fa.y + t2*fd.y,
                   -fa.z - t1*fa.z + t2*fd.z);
        V3 fc = v3(-fa.x - fb.x - fd.x,
                   -fa.y - fb.y - fd.y,
                   -fa.z - fb.z - fd.z);
        addF(Fb, r,     i1, fa);
        addF(Fb, r+o2,  i2, fb);
        addF(Fb, r+o3,  i3, fc);
        addF(Fb, r+o4,  i4, fd);
    }
}

// =====================================================================
// Fully-fused cooperative kernel: 3 Verlet steps, 4 grid syncs total.
// Block b owns residue b (atoms 4b..4b+3, state floats 12b..12b+11), so
// vel -> next pos is block-local (no sync). Pair forces go to Fp
// (block-exclusive, non-atomic); bonded forces atomicAdd into Fb (zeroed
// by the owner in the vel phase).
// =====================================================================
__global__ void __launch_bounds__(NTHR)
sim_kernel(const float* __restrict__ cin, const float* __restrict__ vin,
           const float* __restrict__ masses, const float* __restrict__ ffd,
           const float* __restrict__ ffa, const float* __restrict__ ffdih,
           const int* __restrict__ iflat, const int* __restrict__ ia,
           const int* __restrict__ idh, float* __restrict__ out,
           float* __restrict__ c, float* __restrict__ v, float* __restrict__ al,
           float* __restrict__ Fp, float* __restrict__ Fb)
{
    cg::grid_group grid = cg::this_grid();
    __shared__ float sc[N_ATOMS*3];
    const int tid  = threadIdx.x;
    const int b    = blockIdx.x;
    const int g    = b*NTHR + tid;
    const int lane = tid & 63;
    const int wave = tid >> 6;
    const int j    = b*4 + wave;          // pair-phase output atom (one per wave)

    // ---- phase 0: init + first pos (a_last = 0  =>  c = c_in + v_in*dt) ----
    if (tid < 12) {
        int t = b*12 + tid;
        float vv = vin[t];
        c[t]  = cin[t] + vv*DT;
        v[t]  = vv;
        al[t] = 0.0f;
        Fb[t] = 0.0f;
    }
    __threadfence();
    grid.sync();                                              // sync 1

    for (int s = 0; s < 2; ++s) {
        // ---- force phase: stage coords in LDS, bonded + pair ----
        for (int t = tid; t < N_ATOMS*3; t += NTHR) sc[t] = c[t];
        __syncthreads();

        bonded_item(g, sc, ffa, ffdih, ia, idh, Fb);

        float cx = sc[3*j], cy = sc[3*j+1], cz = sc[3*j+2];
        float fx = 0.0f, fy = 0.0f, fz = 0.0f;
        #pragma unroll
        for (int k = 0; k < 7; ++k) {
            int i = lane + 64*k;
            if (i < N_ATOMS) {
                float dx = cx - sc[3*i];
                float dy = cy - sc[3*i+1];
                float dz = cz - sc[3*i+2];
                float d2 = dx*dx + dy*dy + dz*dz;
                float d  = d2 > 0.0f ? sqrtf(d2) : 0.0f;
                int ind  = bin_dist(d);
                int type = iflat[i*N_ATOMS + j];
                const float* row = ffd + type*140;
                float f = 0.5f*(row[ind] - row[ind+2]);
                float w = f / fmaxf(d, 0.01f);
                fx += w*dx; fy += w*dy; fz += w*dz;
            }
        }
        #pragma unroll
        for (int off = 32; off > 0; off >>= 1) {
            fx += __shfl_down(fx, off);
            fy += __shfl_down(fy, off);
            fz += __shfl_down(fz, off);
        }
        if (lane == 0) { Fp[3*j] = fx; Fp[3*j+1] = fy; Fp[3*j+2] = fz; }
        __threadfence();
        grid.sync();                                          // sync 2 / 4

        // ---- vel (step s) + pos (step s+1), block-local ----
        if (tid < 12) {
            int t = b*12 + tid;
            float a  = (Fp[t] + Fb[t]) / masses[t/3];
            float vv = v[t] + 0.5f*(al[t] + a)*DT;
            v[t]  = vv;
            al[t] = a;
            Fb[t] = 0.0f;                 // ready for next force phase
            float ccur = c[t] + vv*DT + 0.5f*a*DT*DT;
            c[t] = ccur;
            if (s == 1) out[t] = ccur;    // coords after 3rd pos update
        }
        if (s == 0) {
            __threadfence();
            grid.sync();                                      // sync 3
        }
    }
}

// =====================================================================
// Fallback path (previous verified multi-kernel structure) — used only
// if the cooperative launch is rejected (e.g. by graph capture).
// =====================================================================
__global__ void init_kernel(const float* __restrict__ c_in, const float* __restrict__ v_in,
                            float* __restrict__ c, float* __restrict__ v, float* __restrict__ al) {
    int t = blockIdx.x*blockDim.x + threadIdx.x;
    if (t < N_ATOMS*3) { c[t] = c_in[t]; v[t] = v_in[t]; al[t] = 0.0f; }
}

__global__ void pos_kernel(float* __restrict__ c, const float* __restrict__ v,
                           const float* __restrict__ al, float* __restrict__ out) {
    int t = blockIdx.x*blockDim.x + threadIdx.x;
    if (t < N_ATOMS*3) {
        float cc = c[t] + v[t]*DT + 0.5f*al[t]*DT*DT;
        c[t] = cc;
        if (out) out[t] = cc;
    }
}

__global__ void pair_kernel(const float* __restrict__ c, const int* __restrict__ iflat,
                            const float* __restrict__ ffd, float* __restrict__ F) {
    int j = blockIdx.x;
    float cx = c[3*j], cy = c[3*j+1], cz = c[3*j+2];
    float fx = 0.0f, fy = 0.0f, fz = 0.0f;
    for (int i = threadIdx.x; i < N_ATOMS; i += 64) {
        float dx = cx - c[3*i];
        float dy = cy - c[3*i+1];
        float dz = cz - c[3*i+2];
        float d2 = dx*dx + dy*dy + dz*dz;
        float d  = d2 > 0.0f ? sqrtf(d2) : 0.0f;
        int ind  = bin_dist(d);
        int type = iflat[i*N_ATOMS + j];
        const float* row = ffd + type*140;
        float f = 0.5f*(row[ind] - row[ind+2]);
        float w = f / fmaxf(d, 0.01f);
        fx += w*dx; fy += w*dy; fz += w*dz;
    }
    #pragma unroll
    for (int off = 32; off > 0; off >>= 1) {
        fx += __shfl_down(fx, off);
        fy += __shfl_down(fy, off);
        fz += __shfl_down(fz, off);
    }
    if (threadIdx.x == 0) { F[3*j] = fx; F[3*j+1] = fy; F[3*j+2] = fz; }
}

__global__ void bonded_kernel(const float* __restrict__ c, const float* __restrict__ ffa,
                              const float* __restrict__ ffdih, const int* __restrict__ ia,
                              const int* __restrict__ idh, float* __restrict__ F) {
    int t = blockIdx.x*blockDim.x + threadIdx.x;
    if (t < 995) bonded_item(t, c, ffa, ffdih, ia, idh, F);
}

__global__ void vel_kernel(const float* __restrict__ F, const float* __restrict__ masses,
                           float* __restrict__ v, float* __restrict__ al) {
    int t = blockIdx.x*blockDim.x + threadIdx.x;
    if (t < N_ATOMS*3) {
        int atom = t/3;
        float a = F[t] / masses[atom];
        v[t] += 0.5f*(al[t] + a)*DT;
        al[t] = a;
    }
}

extern "C" void kernel_launch(void* const* d_in, const int* in_sizes, int n_in,
                              void* d_out, int out_size, void* d_ws, size_t ws_size,
                              hipStream_t stream) {
    const float* coords = (const float*)d_in[0];
    const float* vels   = (const float*)d_in[1];
    const float* masses = (const float*)d_in[2];
    const float* ffd    = (const float*)d_in[4];   // ff_distances (4000,140)
    const float* ffa    = (const float*)d_in[5];   // ff_angles (5,20,140)
    const float* ffdih  = (const float*)d_in[6];   // ff_dihedrals (5,20,142)
    const int* iflat    = (const int*)d_in[8];     // inters_flat (160000)
    const int* ia       = (const int*)d_in[9];     // inters_ang (100)
    const int* idh      = (const int*)d_in[10];    // inters_dih (100)
    float* out = (float*)d_out;

    float* ws = (float*)d_ws;
    float* c  = ws;
    float* v  = ws + 1200;
    float* al = ws + 2400;
    float* Fp = ws + 3600;
    float* Fb = ws + 4800;

    void* args[] = {
        (void*)&coords, (void*)&vels, (void*)&masses, (void*)&ffd,
        (void*)&ffa, (void*)&ffdih, (void*)&iflat, (void*)&ia,
        (void*)&idh, (void*)&out, (void*)&c, (void*)&v,
        (void*)&al, (void*)&Fp, (void*)&Fb
    };
    hipError_t err = hipLaunchCooperativeKernel((const void*)sim_kernel,
                                                dim3(NBLK), dim3(NTHR),
                                                args, 0, stream);
    if (err != hipSuccess) {
        // fallback: previous verified 10-kernel path
        float* F = Fp;
        init_kernel<<<5, 256, 0, stream>>>(coords, vels, c, v, al);
        const int N_STEPS = 3;
        for (int s = 0; s < N_STEPS; ++s) {
            pos_kernel<<<5, 256, 0, stream>>>(c, v, al, (s == N_STEPS-1) ? out : nullptr);
            if (s < N_STEPS-1) {
                pair_kernel<<<N_ATOMS, 64, 0, stream>>>(c, iflat, ffd, F);
                bonded_kernel<<<4, 256, 0, stream>>>(c, ffa, ffdih, ia, idh, F);
                vel_kernel<<<5, 256, 0, stream>>>(F, masses, v, al);
            }
        }
    }
}

// Round 2
// 98.475 us; speedup vs baseline: 2.0437x; 2.0437x over previous
//
#include <hip/hip_runtime.h>
#include <math.h>

#define N_ATOMS 400
#define N_RES   100
#define DT      0.02f
#define PI_D    3.14159265358979323846
#define NBLK    100
#define NTHR    256

// ---------- small float3 helpers ----------
struct V3 { float x, y, z; };
__device__ __forceinline__ V3 v3(float x, float y, float z) { V3 r{x,y,z}; return r; }
__device__ __forceinline__ V3 sub(V3 a, V3 b) { return v3(a.x-b.x, a.y-b.y, a.z-b.z); }
__device__ __forceinline__ V3 neg(V3 a) { return v3(-a.x, -a.y, -a.z); }
__device__ __forceinline__ V3 scale(V3 a, float s) { return v3(a.x*s, a.y*s, a.z*s); }
__device__ __forceinline__ float dot3(V3 a, V3 b) { return a.x*b.x + a.y*b.y + a.z*b.z; }
__device__ __forceinline__ V3 cross3(V3 a, V3 b) {
    return v3(a.y*b.z - a.z*b.y, a.z*b.x - a.x*b.z, a.x*b.y - a.y*b.x);
}
__device__ __forceinline__ float vnorm(V3 a) {
    float s = dot3(a, a);
    return s > 0.0f ? sqrtf(s) : 0.0f;   // safe_norm semantics
}
__device__ __forceinline__ V3 normalize3(V3 a) {
    float n = fmaxf(vnorm(a), 1e-12f);
    return scale(a, 1.0f/n);
}

// ---------- bin index helpers (uniform grids; argmin == nearest, clamped) ----------
__device__ __forceinline__ int clampi(int i, int lo, int hi) {
    return i < lo ? lo : (i > hi ? hi : i);
}
__device__ __forceinline__ int bin_dist(float d) {
    const float INV = (float)(137.0/14.9);     // linspace(1.0, 15.9, 138)
    return clampi((int)floorf((d - 1.0f)*INV + 0.5f), 0, 137);
}
__device__ __forceinline__ int bin_ang(float a) {
    const float C0  = (float)(PI_D/3.0 + 1.5*((PI_D - PI_D/3.0)/140.0));
    const float INV = (float)(140.0/(PI_D - PI_D/3.0));
    return clampi((int)floorf((a - C0)*INV + 0.5f), 0, 137);
}
__device__ __forceinline__ int bin_dih(float a) {
    const float C0  = (float)(-PI_D + 0.5*(2.0*PI_D/140.0));
    const float INV = (float)(140.0/(2.0*PI_D));
    return clampi((int)floorf((a - C0)*INV + 0.5f), 0, 139);
}

// ---------- bonded-term tables ----------
__constant__ int ANG_I[5][3]   = {{0,1,2},{1,2,0},{2,0,1},{0,1,3},{2,1,3}};
__constant__ int ANG_ACROSS[5] = {0,1,2,0,0};
__constant__ int DIH_I[5][4]   = {{2,0,1,2},{0,1,2,0},{1,2,0,1},{2,0,1,3},{3,1,2,0}};
__constant__ int DIH_ACROSS[5] = {3,1,2,3,1};

__device__ __forceinline__ V3 ldpos(const float* c, int res, int atom) {
    int k = (res*4 + atom)*3;
    return v3(c[k], c[k+1], c[k+2]);
}

// add force f for (res, atom) into this block's LDS force slot IF res == b
__device__ __forceinline__ void addOwn(float* sF, int b, int res, int atom, V3 f) {
    if (res == b) {
        atomicAdd(&sF[atom*3+0], f.x);
        atomicAdd(&sF[atom*3+1], f.y);
        atomicAdd(&sF[atom*3+2], f.z);
    }
}

// Block b evaluates bonded terms at r = b (which=0) and r = b-1 (which=1),
// keeping only contributions that land on residue b. Redundant 2x eval of
// cross-residue terms; total <= 20 tiny term-evals per block.
__device__ __forceinline__ void bonded_own(int u, int b, const float* sc,
                              const float* __restrict__ ffa, const float* __restrict__ ffdih,
                              const int* __restrict__ ia, const int* __restrict__ idh,
                              float* sF) {
    int e = u % 10, which = u / 10;
    int r = b - which;
    if (e < 5) {
        // -------- angles --------
        int across = ANG_ACROSS[e];
        bool valid = which ? (b >= 1 && across != 0)
                           : (across == 0 || b <= N_RES-2);
        if (!valid) return;
        int i1 = ANG_I[e][0], i2 = ANG_I[e][1], i3 = ANG_I[e][2];
        int o2 = (across == 2) ? 1 : 0;
        int o3 = (across != 0) ? 1 : 0;
        V3 p1 = ldpos(sc, r,     i1);
        V3 p2 = ldpos(sc, r+o2,  i2);
        V3 p3 = ldpos(sc, r+o3,  i3);
        V3 ba = sub(p1, p2);
        V3 bc = sub(p3, p2);
        float ban = vnorm(ba), bcn = vnorm(bc);
        float ca = dot3(ba, bc) / (ban*bcn);
        ca = fminf(1.0f, fmaxf(-1.0f, ca));
        float ang = acosf(ca);
        int ind = bin_ang(ang);
        int potr = (across == 2) ? r+1 : r;
        const float* row = ffa + (e*20 + ia[potr])*140;
        float f = 0.5f*(row[ind] - row[ind+2]);
        V3 cr = cross3(ba, bc);
        V3 fa = scale(normalize3(cross3(ba, cr)), f/ban);
        V3 fc = scale(normalize3(neg(cross3(bc, cr))), f/bcn);
        V3 fb = neg(v3(fa.x+fc.x, fa.y+fc.y, fa.z+fc.z));
        addOwn(sF, b, r,     i1, fa);
        addOwn(sF, b, r+o2,  i2, fb);
        addOwn(sF, b, r+o3,  i3, fc);
    } else {
        // -------- dihedrals --------
        int di = e - 5;
        bool valid = which ? (b >= 1) : (b <= N_RES-2);
        if (!valid) return;
        int across = DIH_ACROSS[di];
        int i1 = DIH_I[di][0], i2 = DIH_I[di][1], i3 = DIH_I[di][2], i4 = DIH_I[di][3];
        int o2 = (across == 3) ? 1 : 0;
        int o3 = (across >= 2) ? 1 : 0;
        int o4 = 1;
        V3 p1 = ldpos(sc, r,     i1);
        V3 p2 = ldpos(sc, r+o2,  i2);
        V3 p3 = ldpos(sc, r+o3,  i3);
        V3 p4 = ldpos(sc, r+o4,  i4);
        V3 ab = sub(p2, p1);
        V3 bc = sub(p3, p2);
        V3 cd = sub(p4, p3);
        V3 c1 = cross3(ab, bc);
        V3 c2 = cross3(bc, cd);
        float bcn = vnorm(bc);
        V3 cc = cross3(c1, c2);
        float y = dot3(cc, bc) / bcn;
        float x = dot3(c1, c2);
        float dih = atan2f(y, x);
        int ind = bin_dih(dih);
        int potr = (across == 1) ? r : r+1;
        const float* row = ffdih + (di*20 + idh[potr])*142;
        float f = 0.5f*(row[ind] - row[ind+2]);
        V3 fa = scale(normalize3(neg(c1)), f / vnorm(ab));
        V3 fd = scale(normalize3(c2),      f / vnorm(cd));
        float bsq = bcn*bcn;
        float t1 = dot3(ab, bc)/bsq;
        float t2 = dot3(cd, bc)/bsq;
        V3 fb = v3(-fa.x - t1*fa.x + t2*fd.x,
                   -fa.y - t1*fa.y + t2*fd.y,
                   -fa.z - t1*fa.z + t2*fd.z);
        V3 fc = v3(-fa.x - fb.x - fd.x,
                   -fa.y - fb.y - fd.y,
                   -fa.z - fb.z - fd.z);
        addOwn(sF, b, r,     i1, fa);
        addOwn(sF, b, r+o2,  i2, fb);
        addOwn(sF, b, r+o3,  i3, fc);
        addOwn(sF, b, r+o4,  i4, fd);
    }
}

// Hand-rolled grid barrier: release fetch_add + relaxed spin + one acquire
// load. Cross-block data (coords) moves via agent-scope atomics, so no
// blanket device fence per sync. bar[0] is zeroed by init_kernel each
// iteration (workspace may be re-poisoned between runs). Monotonic, single
// use per launch -> no reset/sense needed. Bounded spin as a hang guard.
__device__ __forceinline__ void grid_barrier(int* bar) {
    __syncthreads();
    if (threadIdx.x == 0) {
        __hip_atomic_fetch_add(bar, 1, __ATOMIC_RELEASE, __HIP_MEMORY_SCOPE_AGENT);
        int iters = 0;
        while (__hip_atomic_load(bar, __ATOMIC_RELAXED, __HIP_MEMORY_SCOPE_AGENT) < NBLK) {
            __builtin_amdgcn_s_sleep(1);
            if (++iters > (1 << 24)) break;   // safety valve; never taken in practice
        }
        (void)__hip_atomic_load(bar, __ATOMIC_ACQUIRE, __HIP_MEMORY_SCOPE_AGENT);
    }
    __syncthreads();
}

// Dispatch 1: first position update (a_last = 0) + barrier-slot zeroing.
// The kernel boundary doubles as the grid-wide sync before the first
// force phase.
__global__ void init_kernel(const float* __restrict__ cin, const float* __restrict__ vin,
                            float* __restrict__ c, int* __restrict__ bar) {
    int t = blockIdx.x*blockDim.x + threadIdx.x;
    if (t < N_ATOMS*3) c[t] = cin[t] + vin[t]*DT;
    if (t < 4) bar[t] = 0;
}

// Dispatch 2: the remaining 2 force phases + 2 integrations, ONE grid
// barrier. Block b owns residue b: its 4 waves compute the 4 atoms' pair
// forces; threads 0..19 redundantly evaluate the bonded terms touching
// residue b. v / a_last / own-coords live in registers of threads 0..11.
__global__ void __launch_bounds__(NTHR)
sim_kernel(const float* __restrict__ vin, const float* __restrict__ masses,
           const float* __restrict__ ffd, const float* __restrict__ ffa,
           const float* __restrict__ ffdih, const int* __restrict__ iflat,
           const int* __restrict__ ia, const int* __restrict__ idh,
           float* __restrict__ out, float* __restrict__ c, int* __restrict__ bar)
{
    __shared__ float sc[N_ATOMS*3];   // staged coords (all atoms)
    __shared__ float sF[12];          // total force on own 4 atoms
    const int tid  = threadIdx.x;
    const int b    = blockIdx.x;
    const int lane = tid & 63;
    const int wave = tid >> 6;
    const int j    = b*4 + wave;      // pair-phase output atom (one per wave)

    float vv = 0.0f, aa = 0.0f;       // owner-thread state (tid < 12)
    if (tid < 12) vv = vin[b*12 + tid];

    for (int s = 0; s < 2; ++s) {
        // ---- stage coords; agent loads stay coherent across XCDs ----
        for (int t = tid; t < N_ATOMS*3; t += NTHR)
            sc[t] = __hip_atomic_load(&c[t], __ATOMIC_RELAXED, __HIP_MEMORY_SCOPE_AGENT);
        if (tid < 12) sF[tid] = 0.0f;
        __syncthreads();

        // ---- bonded forces on own atoms ----
        if (tid < 20) bonded_own(tid, b, sc, ffa, ffdih, ia, idh, sF);

        // ---- pair force for atom j (lanes gather over partners i) ----
        float cx = sc[3*j], cy = sc[3*j+1], cz = sc[3*j+2];
        float fx = 0.0f, fy = 0.0f, fz = 0.0f;
        #pragma unroll
        for (int k = 0; k < 7; ++k) {
            int i = lane + 64*k;
            if (k < 6 || i < N_ATOMS) {
                float dx = cx - sc[3*i];
                float dy = cy - sc[3*i+1];
                float dz = cz - sc[3*i+2];
                float d2 = dx*dx + dy*dy + dz*dz;
                float d  = d2 > 0.0f ? sqrtf(d2) : 0.0f;
                int ind  = bin_dist(d);
                int type = iflat[i*N_ATOMS + j];
                const float* row = ffd + type*140;
                float f = 0.5f*(row[ind] - row[ind+2]);
                float w = f / fmaxf(d, 0.01f);
                fx += w*dx; fy += w*dy; fz += w*dz;
            }
        }
        #pragma unroll
        for (int off = 32; off > 0; off >>= 1) {
            fx += __shfl_down(fx, off);
            fy += __shfl_down(fy, off);
            fz += __shfl_down(fz, off);
        }
        if (lane == 0) {
            atomicAdd(&sF[wave*3+0], fx);
            atomicAdd(&sF[wave*3+1], fy);
            atomicAdd(&sF[wave*3+2], fz);
        }
        __syncthreads();

        // ---- vel (step s) + pos (step s+1): block-local ----
        if (tid < 12) {
            int t = b*12 + tid;
            float a = sF[tid] / masses[b*4 + tid/3];
            vv += 0.5f*(aa + a)*DT;
            aa = a;
            float cc = sc[t] + vv*DT + 0.5f*a*DT*DT;
            if (s == 0)
                __hip_atomic_store(&c[t], cc, __ATOMIC_RELAXED, __HIP_MEMORY_SCOPE_AGENT);
            else
                out[t] = cc;          // coords after 3rd pos update
        }
        if (s == 0) grid_barrier(bar);   // the ONE grid-wide sync
    }
}

extern "C" void kernel_launch(void* const* d_in, const int* in_sizes, int n_in,
                              void* d_out, int out_size, void* d_ws, size_t ws_size,
                              hipStream_t stream) {
    const float* coords = (const float*)d_in[0];
    const float* vels   = (const float*)d_in[1];
    const float* masses = (const float*)d_in[2];
    const float* ffd    = (const float*)d_in[4];   // ff_distances (4000,140)
    const float* ffa    = (const float*)d_in[5];   // ff_angles (5,20,140)
    const float* ffdih  = (const float*)d_in[6];   // ff_dihedrals (5,20,142)
    const int* iflat    = (const int*)d_in[8];     // inters_flat (160000)
    const int* ia       = (const int*)d_in[9];     // inters_ang (100)
    const int* idh      = (const int*)d_in[10];    // inters_dih (100)
    float* out = (float*)d_out;

    float* ws  = (float*)d_ws;
    float* c   = ws;                   // 1200 floats: live coords
    int*   bar = (int*)(ws + 1200);    // barrier slots

    init_kernel<<<5, 256, 0, stream>>>(coords, vels, c, bar);
    sim_kernel<<<NBLK, NTHR, 0, stream>>>(vels, masses, ffd, ffa, ffdih,
                                          iflat, ia, idh, out, c, bar);
}

// Round 3
// 92.711 us; speedup vs baseline: 2.1708x; 1.0622x over previous
//
#include <hip/hip_runtime.h>
#include <math.h>

#define N_ATOMS 400
#define N_RES   100
#define DT      0.02f
#define PI_D    3.14159265358979323846
#define NBLK    100
#define NTHR    256

// ---------- small float3 helpers ----------
struct V3 { float x, y, z; };
__device__ __forceinline__ V3 v3(float x, float y, float z) { V3 r{x,y,z}; return r; }
__device__ __forceinline__ V3 sub(V3 a, V3 b) { return v3(a.x-b.x, a.y-b.y, a.z-b.z); }
__device__ __forceinline__ V3 neg(V3 a) { return v3(-a.x, -a.y, -a.z); }
__device__ __forceinline__ V3 scale(V3 a, float s) { return v3(a.x*s, a.y*s, a.z*s); }
__device__ __forceinline__ float dot3(V3 a, V3 b) { return a.x*b.x + a.y*b.y + a.z*b.z; }
__device__ __forceinline__ V3 cross3(V3 a, V3 b) {
    return v3(a.y*b.z - a.z*b.y, a.z*b.x - a.x*b.z, a.x*b.y - a.y*b.x);
}
__device__ __forceinline__ float vnorm(V3 a) {
    float s = dot3(a, a);
    return s > 0.0f ? sqrtf(s) : 0.0f;   // safe_norm semantics
}
__device__ __forceinline__ V3 normalize3(V3 a) {
    float n = fmaxf(vnorm(a), 1e-12f);
    return scale(a, 1.0f/n);
}

// ---------- bin index helpers (uniform grids; argmin == nearest, clamped) ----------
__device__ __forceinline__ int clampi(int i, int lo, int hi) {
    return i < lo ? lo : (i > hi ? hi : i);
}
__device__ __forceinline__ int bin_dist(float d) {
    const float INV = (float)(137.0/14.9);     // linspace(1.0, 15.9, 138)
    return clampi((int)floorf((d - 1.0f)*INV + 0.5f), 0, 137);
}
__device__ __forceinline__ int bin_ang(float a) {
    const float C0  = (float)(PI_D/3.0 + 1.5*((PI_D - PI_D/3.0)/140.0));
    const float INV = (float)(140.0/(PI_D - PI_D/3.0));
    return clampi((int)floorf((a - C0)*INV + 0.5f), 0, 137);
}
__device__ __forceinline__ int bin_dih(float a) {
    const float C0  = (float)(-PI_D + 0.5*(2.0*PI_D/140.0));
    const float INV = (float)(140.0/(2.0*PI_D));
    return clampi((int)floorf((a - C0)*INV + 0.5f), 0, 139);
}

// ---------- bonded-term tables ----------
__constant__ int ANG_I[5][3]   = {{0,1,2},{1,2,0},{2,0,1},{0,1,3},{2,1,3}};
__constant__ int ANG_ACROSS[5] = {0,1,2,0,0};
__constant__ int DIH_I[5][4]   = {{2,0,1,2},{0,1,2,0},{1,2,0,1},{2,0,1,3},{3,1,2,0}};
__constant__ int DIH_ACROSS[5] = {3,1,2,3,1};

__device__ __forceinline__ V3 ldpos(const float* c, int res, int atom) {
    int k = (res*4 + atom)*3;
    return v3(c[k], c[k+1], c[k+2]);
}

// add force f for (res, atom) into this block's LDS force slot IF res == b
__device__ __forceinline__ void addOwn(float* sF, int b, int res, int atom, V3 f) {
    if (res == b) {
        atomicAdd(&sF[atom*3+0], f.x);
        atomicAdd(&sF[atom*3+1], f.y);
        atomicAdd(&sF[atom*3+2], f.z);
    }
}

// Block b evaluates bonded terms at r = b (which=0) and r = b-1 (which=1),
// keeping only contributions that land on residue b. Redundant 2x eval of
// cross-residue terms; total <= 20 tiny term-evals per block.
__device__ __forceinline__ void bonded_own(int u, int b, const float* sc,
                              const float* __restrict__ ffa, const float* __restrict__ ffdih,
                              const int* __restrict__ ia, const int* __restrict__ idh,
                              float* sF) {
    int e = u % 10, which = u / 10;
    int r = b - which;
    if (e < 5) {
        // -------- angles --------
        int across = ANG_ACROSS[e];
        bool valid = which ? (b >= 1 && across != 0)
                           : (across == 0 || b <= N_RES-2);
        if (!valid) return;
        int i1 = ANG_I[e][0], i2 = ANG_I[e][1], i3 = ANG_I[e][2];
        int o2 = (across == 2) ? 1 : 0;
        int o3 = (across != 0) ? 1 : 0;
        V3 p1 = ldpos(sc, r,     i1);
        V3 p2 = ldpos(sc, r+o2,  i2);
        V3 p3 = ldpos(sc, r+o3,  i3);
        V3 ba = sub(p1, p2);
        V3 bc = sub(p3, p2);
        float ban = vnorm(ba), bcn = vnorm(bc);
        float ca = dot3(ba, bc) / (ban*bcn);
        ca = fminf(1.0f, fmaxf(-1.0f, ca));
        float ang = acosf(ca);
        int ind = bin_ang(ang);
        int potr = (across == 2) ? r+1 : r;
        const float* row = ffa + (e*20 + ia[potr])*140;
        float f = 0.5f*(row[ind] - row[ind+2]);
        V3 cr = cross3(ba, bc);
        V3 fa = scale(normalize3(cross3(ba, cr)), f/ban);
        V3 fc = scale(normalize3(neg(cross3(bc, cr))), f/bcn);
        V3 fb = neg(v3(fa.x+fc.x, fa.y+fc.y, fa.z+fc.z));
        addOwn(sF, b, r,     i1, fa);
        addOwn(sF, b, r+o2,  i2, fb);
        addOwn(sF, b, r+o3,  i3, fc);
    } else {
        // -------- dihedrals --------
        int di = e - 5;
        bool valid = which ? (b >= 1) : (b <= N_RES-2);
        if (!valid) return;
        int across = DIH_ACROSS[di];
        int i1 = DIH_I[di][0], i2 = DIH_I[di][1], i3 = DIH_I[di][2], i4 = DIH_I[di][3];
        int o2 = (across == 3) ? 1 : 0;
        int o3 = (across >= 2) ? 1 : 0;
        int o4 = 1;
        V3 p1 = ldpos(sc, r,     i1);
        V3 p2 = ldpos(sc, r+o2,  i2);
        V3 p3 = ldpos(sc, r+o3,  i3);
        V3 p4 = ldpos(sc, r+o4,  i4);
        V3 ab = sub(p2, p1);
        V3 bc = sub(p3, p2);
        V3 cd = sub(p4, p3);
        V3 c1 = cross3(ab, bc);
        V3 c2 = cross3(bc, cd);
        float bcn = vnorm(bc);
        V3 cc = cross3(c1, c2);
        float y = dot3(cc, bc) / bcn;
        float x = dot3(c1, c2);
        float dih = atan2f(y, x);
        int ind = bin_dih(dih);
        int potr = (across == 1) ? r : r+1;
        const float* row = ffdih + (di*20 + idh[potr])*142;
        float f = 0.5f*(row[ind] - row[ind+2]);
        V3 fa = scale(normalize3(neg(c1)), f / vnorm(ab));
        V3 fd = scale(normalize3(c2),      f / vnorm(cd));
        float bsq = bcn*bcn;
        float t1 = dot3(ab, bc)/bsq;
        float t2 = dot3(cd, bc)/bsq;
        V3 fb = v3(-fa.x - t1*fa.x + t2*fd.x,
                   -fa.y - t1*fa.y + t2*fd.y,
                   -fa.z - t1*fa.z + t2*fd.z);
        V3 fc = v3(-fa.x - fb.x - fd.x,
                   -fa.y - fb.y - fd.y,
                   -fa.z - fb.z - fd.z);
        addOwn(sF, b, r,     i1, fa);
        addOwn(sF, b, r+o2,  i2, fb);
        addOwn(sF, b, r+o3,  i3, fc);
        addOwn(sF, b, r+o4,  i4, fd);
    }
}

// Force phase shared by both kernels: bonded (threads 0..19) + pair (one
// wave per own atom, types prefetched in ty[7]); result accumulated in sF[12].
__device__ __forceinline__ void force_phase(int b, int tid, int lane, int wave,
                              const float* sc, float* sF, const int* ty,
                              const float* __restrict__ ffd, const float* __restrict__ ffa,
                              const float* __restrict__ ffdih, const int* __restrict__ ia,
                              const int* __restrict__ idh) {
    if (tid < 20) bonded_own(tid, b, sc, ffa, ffdih, ia, idh, sF);

    int j = b*4 + wave;
    float cx = sc[3*j], cy = sc[3*j+1], cz = sc[3*j+2];
    float fx = 0.0f, fy = 0.0f, fz = 0.0f;
    #pragma unroll
    for (int k = 0; k < 7; ++k) {
        int i = lane + 64*k;
        if (k < 6 || i < N_ATOMS) {
            float dx = cx - sc[3*i];
            float dy = cy - sc[3*i+1];
            float dz = cz - sc[3*i+2];
            float d2 = dx*dx + dy*dy + dz*dz;
            float d  = d2 > 0.0f ? sqrtf(d2) : 0.0f;
            int ind  = bin_dist(d);
            const float* row = ffd + ty[k]*140;
            float f = 0.5f*(row[ind] - row[ind+2]);
            float w = f / fmaxf(d, 0.01f);
            fx += w*dx; fy += w*dy; fz += w*dz;
        }
    }
    #pragma unroll
    for (int off = 32; off > 0; off >>= 1) {
        fx += __shfl_down(fx, off);
        fy += __shfl_down(fy, off);
        fz += __shfl_down(fz, off);
    }
    if (lane == 0) {
        atomicAdd(&sF[wave*3+0], fx);
        atomicAdd(&sF[wave*3+1], fy);
        atomicAdd(&sF[wave*3+2], fz);
    }
}

// Kernel A: every block redundantly computes c1 = cin + vin*DT for ALL
// atoms (elementwise, cheap) directly into LDS -> no init kernel, no
// grid barrier. Then force phase on c1, own vel/accel, own c2; writes
// c2/v1/a1 for its 4 atoms. The A->B kernel boundary provides the
// grid-wide sync + cache coherence (HSA release/acquire).
__global__ void __launch_bounds__(NTHR)
stepA(const float* __restrict__ cin, const float* __restrict__ vin,
      const float* __restrict__ masses, const float* __restrict__ ffd,
      const float* __restrict__ ffa, const float* __restrict__ ffdih,
      const int* __restrict__ iflat, const int* __restrict__ ia,
      const int* __restrict__ idh, float* __restrict__ c2,
      float* __restrict__ v1, float* __restrict__ a1)
{
    __shared__ float sc[N_ATOMS*3];
    __shared__ float sF[12];
    const int tid  = threadIdx.x;
    const int b    = blockIdx.x;
    const int lane = tid & 63;
    const int wave = tid >> 6;
    const int j    = b*4 + wave;

    // prefetch pair types (step-invariant; off the critical path)
    int ty[7];
    #pragma unroll
    for (int k = 0; k < 7; ++k) {
        int i = lane + 64*k;
        ty[k] = (k < 6 || i < N_ATOMS) ? iflat[i*N_ATOMS + j] : 0;
    }

    // c1 for ALL atoms, float4-vectorized (1200 floats = 300 float4)
    for (int q = tid; q < 300; q += NTHR) {
        float4 cv = ((const float4*)cin)[q];
        float4 vv = ((const float4*)vin)[q];
        float4 r;
        r.x = cv.x + vv.x*DT; r.y = cv.y + vv.y*DT;
        r.z = cv.z + vv.z*DT; r.w = cv.w + vv.w*DT;
        ((float4*)sc)[q] = r;
    }
    if (tid < 12) sF[tid] = 0.0f;
    __syncthreads();

    force_phase(b, tid, lane, wave, sc, sF, ty, ffd, ffa, ffdih, ia, idh);
    __syncthreads();

    if (tid < 12) {
        int t = b*12 + tid;
        float a = sF[tid] / masses[b*4 + tid/3];
        float v = vin[t] + 0.5f*a*DT;                    // a_last = 0
        float cc = sc[t] + v*DT + 0.5f*a*DT*DT;
        c2[t] = cc; v1[t] = v; a1[t] = a;
    }
}

// Kernel B: stage c2 (plain coalesced loads — coherent across the kernel
// boundary), force phase, final integration, write c3 to out.
__global__ void __launch_bounds__(NTHR)
stepB(const float* __restrict__ masses, const float* __restrict__ ffd,
      const float* __restrict__ ffa, const float* __restrict__ ffdih,
      const int* __restrict__ iflat, const int* __restrict__ ia,
      const int* __restrict__ idh, const float* __restrict__ c2,
      const float* __restrict__ v1, const float* __restrict__ a1,
      float* __restrict__ out)
{
    __shared__ float sc[N_ATOMS*3];
    __shared__ float sF[12];
    const int tid  = threadIdx.x;
    const int b    = blockIdx.x;
    const int lane = tid & 63;
    const int wave = tid >> 6;
    const int j    = b*4 + wave;

    int ty[7];
    #pragma unroll
    for (int k = 0; k < 7; ++k) {
        int i = lane + 64*k;
        ty[k] = (k < 6 || i < N_ATOMS) ? iflat[i*N_ATOMS + j] : 0;
    }

    for (int q = tid; q < 300; q += NTHR)
        ((float4*)sc)[q] = ((const float4*)c2)[q];
    if (tid < 12) sF[tid] = 0.0f;
    __syncthreads();

    force_phase(b, tid, lane, wave, sc, sF, ty, ffd, ffa, ffdih, ia, idh);
    __syncthreads();

    if (tid < 12) {
        int t = b*12 + tid;
        float a = sF[tid] / masses[b*4 + tid/3];
        float v = v1[t] + 0.5f*(a1[t] + a)*DT;
        out[t] = sc[t] + v*DT + 0.5f*a*DT*DT;            // c3
    }
}

extern "C" void kernel_launch(void* const* d_in, const int* in_sizes, int n_in,
                              void* d_out, int out_size, void* d_ws, size_t ws_size,
                              hipStream_t stream) {
    const float* coords = (const float*)d_in[0];
    const float* vels   = (const float*)d_in[1];
    const float* masses = (const float*)d_in[2];
    const float* ffd    = (const float*)d_in[4];   // ff_distances (4000,140)
    const float* ffa    = (const float*)d_in[5];   // ff_angles (5,20,140)
    const float* ffdih  = (const float*)d_in[6];   // ff_dihedrals (5,20,142)
    const int* iflat    = (const int*)d_in[8];     // inters_flat (160000)
    const int* ia       = (const int*)d_in[9];     // inters_ang (100)
    const int* idh      = (const int*)d_in[10];    // inters_dih (100)
    float* out = (float*)d_out;

    float* ws = (float*)d_ws;
    float* c2 = ws;          // 1200 floats: coords after 2nd pos update
    float* v1 = ws + 1200;   // 1200 floats: vel after 1st step
    float* a1 = ws + 2400;   // 1200 floats: accel of 1st step

    stepA<<<NBLK, NTHR, 0, stream>>>(coords, vels, masses, ffd, ffa, ffdih,
                                     iflat, ia, idh, c2, v1, a1);
    stepB<<<NBLK, NTHR, 0, stream>>>(masses, ffd, ffa, ffdih,
                                     iflat, ia, idh, c2, v1, a1, out);
}